// Round 7
// baseline (353.137 us; speedup 1.0000x reference)
//
#include <hip/hip_runtime.h>
#include <hip/hip_bf16.h>

#define NT 8192
#define DIM 512
#define NE 16

#define BM 256
#define BN 256
#define BK 64
#define NKT 8   // DIM / BK

typedef __attribute__((ext_vector_type(4))) float f32x4;
typedef __attribute__((ext_vector_type(8))) short short8;

typedef __attribute__((address_space(3))) void lds_void_t;
typedef const __attribute__((address_space(1))) void g_void_t;

__device__ inline unsigned short f2b(float f) {
  union { __hip_bfloat16 b; unsigned short u; } cv;
  cv.b = __float2bfloat16(f);  // RNE
  return cv.u;
}

// Convert x [NT*DIM] and W [NE*DIM*DIM] fp32 -> bf16 into workspace.
__global__ __launch_bounds__(256) void cvt_kernel(const float* __restrict__ x,
                                                  const float* __restrict__ W,
                                                  unsigned short* __restrict__ xb,
                                                  unsigned short* __restrict__ wb) {
  long t = (long)blockIdx.x * 256 + threadIdx.x;
  long i = t * 8;
  const float* src;
  unsigned short* dst;
  if (i < (long)NT * DIM) {
    src = x + i;
    dst = xb + i;
  } else {
    long j = i - (long)NT * DIM;
    src = W + j;
    dst = wb + j;
  }
  float4 v0 = reinterpret_cast<const float4*>(src)[0];
  float4 v1 = reinterpret_cast<const float4*>(src)[1];
  short8 o;
  o[0] = (short)f2b(v0.x); o[1] = (short)f2b(v0.y);
  o[2] = (short)f2b(v0.z); o[3] = (short)f2b(v0.w);
  o[4] = (short)f2b(v1.x); o[5] = (short)f2b(v1.y);
  o[6] = (short)f2b(v1.z); o[7] = (short)f2b(v1.w);
  *reinterpret_cast<short8*>(dst) = o;
}

#define GLOAD(gp, lp) __builtin_amdgcn_global_load_lds((g_void_t*)(gp), (lds_void_t*)(lp), 16, 0, 0)

// C[e] = x @ W[e]^T + b[e].
// 256x256 tile, BK=64, 8 waves (2M x 4N), double-buffered LDS (128 KiB).
// Fine-interleaved pipeline: 2 global_load_lds per phase, counted vmcnt(2)
// at tile boundary (never 0 in steady state), 2 barriers/tile, zig-zag
// phase order (A0B0, A1B0, A1B1, A0B1 -> 24 ds_reads/tile), XOR-swizzled
// LDS (pre-swizzled global source, swizzled ds_read), setprio around MFMA,
// XCD-chunked block swizzle.
__global__ __launch_bounds__(512, 2) void expert_gemm(const unsigned short* __restrict__ xb,
                                                      const unsigned short* __restrict__ wb,
                                                      const float* __restrict__ bias,
                                                      float* __restrict__ out) {
  extern __shared__ char smem[];  // 2 * (32KB A + 32KB B) = 131072 B

  const int tid  = threadIdx.x;
  const int lane = tid & 63;
  const int w    = tid >> 6;     // 0..7
  const int wr   = w >> 2;       // 0..1  (128-row band)
  const int wc   = w & 3;        // 0..3  (64-col band)

  // XCD-chunked swizzle: grid 1024, 8 XCDs, 128 contiguous orig-bids per XCD.
  const int bid0 = blockIdx.x;
  const int bid  = (bid0 & 7) * 128 + (bid0 >> 3);
  const int e   = bid >> 6;        // e(16) * tn(2) * tm(32)
  const int tn  = (bid >> 5) & 1;
  const int tm  = bid & 31;

  const int m0 = tm * BM;
  const int n0 = tn * BN;

  const unsigned short* Ag = xb + (size_t)m0 * DIM;
  const unsigned short* Bg = wb + (size_t)e * DIM * DIM + (size_t)n0 * DIM;

  // ---- staging geometry (per lane) ---- [verified round 4]
  // instr j of wave w writes LDS bytes [(w*4+j)*1024, +1024); lane l writes +l*16.
  // Linear LDS layout: [256 rows][64 cols bf16]; swizzle: LDS pos p of row r
  // holds source chunk (p ^ (r&7)) -> pre-swizzle the global source column.
  const int slrow = lane >> 3;                     // row-within-8 for this lane
  const int scol  = ((lane & 7) ^ slrow) * 8;      // pre-swizzled source column (elems)

  // ---- fragment read geometry ---- [verified round 4]
  const int q  = lane >> 4;      // 0..3 -> k offset q*8
  const int fr = lane & 15;      // fragment row/col
  const int axor = fr & 7;       // row&7 for all frag rows (row ≡ fr mod 8)
  const int cx0 = ((0 * 4 + q) ^ axor) << 4;       // kk=0 swizzled byte offset
  const int cx1 = ((1 * 4 + q) ^ axor) << 4;       // kk=1

  f32x4 acc[8][4] = {};   // [mi 0..7][ni 0..3] -> wave's 128x64 output
  short8 a0[4][2];        // A frags mh=0 (rows wr*128 + 0..63)
  short8 a1[4][2];        // A frags mh=1 (rows wr*128 + 64..127)
  short8 b[2][2];         // B frags for current nh

  // per-wave staging rows: A instr j covers rows (w*4+j)*8 + slrow
  const int grow0 = (w * 4 + 0) * 8 + slrow;
  const int grow1 = (w * 4 + 1) * 8 + slrow;
  const int grow2 = (w * 4 + 2) * 8 + slrow;
  const int grow3 = (w * 4 + 3) * 8 + slrow;

  // ---- prologue: stage tile 0 into buf0 (no wait yet) ----
  {
    char* lA = smem;
    char* lB = smem + 32768;
    GLOAD(Ag + (size_t)grow0 * DIM + scol, lA + (w * 4 + 0) * 1024);
    GLOAD(Bg + (size_t)grow0 * DIM + scol, lB + (w * 4 + 0) * 1024);
    GLOAD(Ag + (size_t)grow1 * DIM + scol, lA + (w * 4 + 1) * 1024);
    GLOAD(Bg + (size_t)grow1 * DIM + scol, lB + (w * 4 + 1) * 1024);
    GLOAD(Ag + (size_t)grow2 * DIM + scol, lA + (w * 4 + 2) * 1024);
    GLOAD(Bg + (size_t)grow2 * DIM + scol, lB + (w * 4 + 2) * 1024);
    GLOAD(Ag + (size_t)grow3 * DIM + scol, lA + (w * 4 + 3) * 1024);
    GLOAD(Bg + (size_t)grow3 * DIM + scol, lB + (w * 4 + 3) * 1024);
  }

#pragma unroll 1
  for (int kt = 0; kt < NKT; ++kt) {
    const int cur = kt & 1;
    const char* lA = smem + cur * 65536;
    const char* lB = lA + 32768;
    char* nA = smem + (cur ^ 1) * 65536;   // staging dest for tile kt+1
    char* nB = nA + 32768;
    const int kc = (kt + 1) * BK + scol;   // source col for tile kt+1

    // ---- tile boundary ----
    // barrier1: all waves' reads of buf[cur^1] (tile kt-1) are done,
    // safe to start overwriting it with tile kt+1.
    asm volatile("" ::: "memory");
    __builtin_amdgcn_s_barrier();
    asm volatile("" ::: "memory");
    if (kt + 1 < NKT) {
      // pair 0 for tile kt+1, issued BEFORE the counted wait so the queue
      // never drains in steady state.
      GLOAD(Ag + (size_t)grow0 * DIM + kc, nA + (w * 4 + 0) * 1024);
      GLOAD(Bg + (size_t)grow0 * DIM + kc, nB + (w * 4 + 0) * 1024);
      asm volatile("s_waitcnt vmcnt(2)" ::: "memory");  // tile kt fully landed
    } else {
      asm volatile("s_waitcnt vmcnt(0)" ::: "memory");  // tail drain
    }
    // barrier2: every wave's tile-kt data is in LDS
    __builtin_amdgcn_s_barrier();
    asm volatile("" ::: "memory");

    // ---- phase 0: read A0 + B0, MFMA (A0,B0) -> acc[0..3][0..1] ----
#pragma unroll
    for (int mi = 0; mi < 4; ++mi) {
      const int ra = wr * 128 + mi * 16 + fr;
      a0[mi][0] = *reinterpret_cast<const short8*>(lA + ra * 128 + cx0);
      a0[mi][1] = *reinterpret_cast<const short8*>(lA + ra * 128 + cx1);
    }
#pragma unroll
    for (int ni = 0; ni < 2; ++ni) {
      const int rb = wc * 64 + ni * 16 + fr;
      b[ni][0] = *reinterpret_cast<const short8*>(lB + rb * 128 + cx0);
      b[ni][1] = *reinterpret_cast<const short8*>(lB + rb * 128 + cx1);
    }
    __builtin_amdgcn_s_setprio(1);
#pragma unroll
    for (int kk = 0; kk < 2; ++kk)
#pragma unroll
      for (int mi = 0; mi < 4; ++mi)
#pragma unroll
        for (int ni = 0; ni < 2; ++ni)
          acc[mi][ni] = __builtin_amdgcn_mfma_f32_16x16x32_bf16(a0[mi][kk], b[ni][kk], acc[mi][ni], 0, 0, 0);
    __builtin_amdgcn_s_setprio(0);

    // ---- phase 1: GLOAD pair1; read A1; MFMA (A1,B0) -> acc[4..7][0..1] ----
    if (kt + 1 < NKT) {
      GLOAD(Ag + (size_t)grow1 * DIM + kc, nA + (w * 4 + 1) * 1024);
      GLOAD(Bg + (size_t)grow1 * DIM + kc, nB + (w * 4 + 1) * 1024);
    }
#pragma unroll
    for (int mi = 0; mi < 4; ++mi) {
      const int ra = wr * 128 + 64 + mi * 16 + fr;
      a1[mi][0] = *reinterpret_cast<const short8*>(lA + ra * 128 + cx0);
      a1[mi][1] = *reinterpret_cast<const short8*>(lA + ra * 128 + cx1);
    }
    __builtin_amdgcn_s_setprio(1);
#pragma unroll
    for (int kk = 0; kk < 2; ++kk)
#pragma unroll
      for (int mi = 0; mi < 4; ++mi)
#pragma unroll
        for (int ni = 0; ni < 2; ++ni)
          acc[4 + mi][ni] = __builtin_amdgcn_mfma_f32_16x16x32_bf16(a1[mi][kk], b[ni][kk], acc[4 + mi][ni], 0, 0, 0);
    __builtin_amdgcn_s_setprio(0);

    // ---- phase 2: GLOAD pair2; read B1; MFMA (A1,B1) -> acc[4..7][2..3] ----
    if (kt + 1 < NKT) {
      GLOAD(Ag + (size_t)grow2 * DIM + kc, nA + (w * 4 + 2) * 1024);
      GLOAD(Bg + (size_t)grow2 * DIM + kc, nB + (w * 4 + 2) * 1024);
    }
#pragma unroll
    for (int ni = 0; ni < 2; ++ni) {
      const int rb = wc * 64 + 32 + ni * 16 + fr;
      b[ni][0] = *reinterpret_cast<const short8*>(lB + rb * 128 + cx0);
      b[ni][1] = *reinterpret_cast<const short8*>(lB + rb * 128 + cx1);
    }
    __builtin_amdgcn_s_setprio(1);
#pragma unroll
    for (int kk = 0; kk < 2; ++kk)
#pragma unroll
      for (int mi = 0; mi < 4; ++mi)
#pragma unroll
        for (int ni = 0; ni < 2; ++ni)
          acc[4 + mi][2 + ni] = __builtin_amdgcn_mfma_f32_16x16x32_bf16(a1[mi][kk], b[ni][kk], acc[4 + mi][2 + ni], 0, 0, 0);
    __builtin_amdgcn_s_setprio(0);

    // ---- phase 3: GLOAD pair3; MFMA (A0,B1) -> acc[0..3][2..3] ----
    if (kt + 1 < NKT) {
      GLOAD(Ag + (size_t)grow3 * DIM + kc, nA + (w * 4 + 3) * 1024);
      GLOAD(Bg + (size_t)grow3 * DIM + kc, nB + (w * 4 + 3) * 1024);
    }
    __builtin_amdgcn_s_setprio(1);
#pragma unroll
    for (int kk = 0; kk < 2; ++kk)
#pragma unroll
      for (int mi = 0; mi < 4; ++mi)
#pragma unroll
        for (int ni = 0; ni < 2; ++ni)
          acc[mi][2 + ni] = __builtin_amdgcn_mfma_f32_16x16x32_bf16(a0[mi][kk], b[ni][kk], acc[mi][2 + ni], 0, 0, 0);
    __builtin_amdgcn_s_setprio(0);
  }

  // ---- epilogue: C row = q*4 + reg, col = fr (verified mapping); fused bias ----
  float bv[4];
#pragma unroll
  for (int ni = 0; ni < 4; ++ni)
    bv[ni] = bias[e * DIM + n0 + wc * 64 + ni * 16 + fr];

  float* outE = out + (size_t)e * NT * DIM;
#pragma unroll
  for (int mi = 0; mi < 8; ++mi) {
#pragma unroll
    for (int reg = 0; reg < 4; ++reg) {
      const int row = m0 + wr * 128 + mi * 16 + q * 4 + reg;
      float* op = outE + (size_t)row * DIM + n0 + wc * 64 + fr;
#pragma unroll
      for (int ni = 0; ni < 4; ++ni)
        op[ni * 16] = acc[mi][ni][reg] + bv[ni];
    }
  }
}

extern "C" void kernel_launch(void* const* d_in, const int* in_sizes, int n_in,
                              void* d_out, int out_size, void* d_ws, size_t ws_size,
                              hipStream_t stream) {
  const float* x = (const float*)d_in[0];
  const float* W = (const float*)d_in[1];
  const float* b = (const float*)d_in[2];
  float* out = (float*)d_out;

  unsigned short* xb = (unsigned short*)d_ws;                 // 8 MB
  unsigned short* wb = xb + (size_t)NT * DIM;                 // 8 MB

  // (NT*DIM + NE*DIM*DIM) / 8 elems-per-thread / 256 threads = 4096 blocks
  cvt_kernel<<<4096, 256, 0, stream>>>(x, W, xb, wb);

  // allow 128 KiB dynamic LDS (idempotent; host-side, graph-capture-safe)
  (void)hipFuncSetAttribute(reinterpret_cast<const void*>(expert_gemm),
                            hipFuncAttributeMaxDynamicSharedMemorySize, 131072);

  // 16 experts * 2 n-tiles * 32 m-tiles = 1024 blocks, 512 threads, 128 KiB LDS
  expert_gemm<<<1024, 512, 131072, stream>>>(xb, wb, b, out);
}